// Round 1
// baseline (174.800 us; speedup 1.0000x reference)
//
#include <hip/hip_runtime.h>
#include <stdint.h>

#define AS1 __attribute__((address_space(1)))
#define AS3 __attribute__((address_space(3)))

typedef float f32x4 __attribute__((ext_vector_type(4)));
typedef __bf16 bf16x8 __attribute__((ext_vector_type(8)));

// fp32 -> bf16, round-to-nearest-even (inputs are finite; no NaN handling needed)
__device__ __forceinline__ unsigned short f2bf(float f) {
    uint32_t x = __float_as_uint(f);
    x += 0x7FFFu + ((x >> 16) & 1u);
    return (unsigned short)(x >> 16);
}

__device__ __forceinline__ void gload_lds16(const void* g, void* l) {
    __builtin_amdgcn_global_load_lds((const AS1 void*)g, (AS3 void*)l, 16, 0, 0);
}

// ---------------------------------------------------------------------------
// Kernel 0: WT[n][f] = bf16(W[f][n]).  W is [256][256] fp32 row-major.
// ---------------------------------------------------------------------------
__global__ __launch_bounds__(256) void wt_kernel(const float* __restrict__ W,
                                                 unsigned short* __restrict__ WT) {
    __shared__ float tile[32][33];
    const int bf = blockIdx.x & 7;   // f-tile
    const int bn = blockIdx.x >> 3;  // n-tile
    const int t = threadIdx.x;
    const int c = t & 31, r = t >> 5;  // r in 0..7
#pragma unroll
    for (int i = 0; i < 4; ++i)
        tile[r + i * 8][c] = W[(bf * 32 + r + i * 8) * 256 + bn * 32 + c];
    __syncthreads();
#pragma unroll
    for (int i = 0; i < 4; ++i)
        WT[(bn * 32 + r + i * 8) * 256 + bf * 32 + c] = f2bf(tile[c][r + i * 8]);
}

// ---------------------------------------------------------------------------
// GEMM: D[m][n] = sum_k A[m][k] * B[n][k]   (B given row-major over n, i.e. B^T)
//   A: fp32, converted to bf16 in-flight (reg-stage + swizzled ds_write)
//   B: bf16, staged via global_load_lds with pre-swizzled per-lane source
// Tile: BM=32, BN=256 (full N), BK=64. 256 threads = 4 waves, wave tile 32x64.
// MODE 0: relu + fp32 store to Out[m][n] (ld 256)
// MODE 1: bf16 transposed store Out[n][m] (ld 8192)
// ---------------------------------------------------------------------------
template <int LDA, int LDB, int KSTEPS, int MODE>
__global__ __launch_bounds__(256) void gemm_kernel(const float* __restrict__ A,
                                                   const unsigned short* __restrict__ B,
                                                   void* __restrict__ Outp) {
    __shared__ unsigned short Alds[32 * 64];   // 4 KB  (swizzled rows, stride 128 B)
    __shared__ unsigned short Blds[256 * 64];  // 32 KB (swizzled rows, stride 128 B)

    const int t = threadIdx.x;
    const int w = t >> 6;
    const int l = t & 63;
    const int m0 = blockIdx.x * 32;

    // A staging mapping: thread t loads row ar, k in [kq*4, kq*4+4) and [32+kq*4, ...)
    const int ar = t >> 3;  // 0..31
    const int kq = t & 7;   // 0..7
    const float* gA = A + (size_t)(m0 + ar) * LDA + kq * 4;
    char* aw0 = (char*)Alds + ((ar * 128 + kq * 8) ^ ((ar & 7) << 4));
    char* aw1 = (char*)Alds + ((ar * 128 + 64 + kq * 8) ^ ((ar & 7) << 4));

    // B staging mapping: per issue i, lane covers chunk c = w*512 + i*64 + l
    const int nr_base = w * 64 + (l >> 3);  // + i*8 per issue
    const int c16 = l & 7;

    f32x4 acc[2][4];
#pragma unroll
    for (int i = 0; i < 2; ++i)
#pragma unroll
        for (int j = 0; j < 4; ++j) acc[i][j] = (f32x4){0.f, 0.f, 0.f, 0.f};

    for (int step = 0; step < KSTEPS; ++step) {
        const int k0 = step * 64;
        __syncthreads();
        // ---- B tile: [256 n][64 k] bf16 via global_load_lds (linear dest,
        //      swizzle achieved by XORing the SOURCE k-chunk with row&7)
#pragma unroll
        for (int i = 0; i < 8; ++i) {
            const int nr = nr_base + i * 8;
            const unsigned short* src =
                B + (size_t)nr * LDB + k0 + ((c16 ^ (nr & 7)) << 3);
            gload_lds16(src, (char*)Blds + (w * 512 + i * 64) * 16);
        }
        // ---- A tile: [32 m][64 k] fp32 -> bf16, swizzled ds_write
        const f32x4 v0 = *(const f32x4*)(gA + k0);
        const f32x4 v1 = *(const f32x4*)(gA + k0 + 32);
        uint32_t p0 = (uint32_t)f2bf(v0.x) | ((uint32_t)f2bf(v0.y) << 16);
        uint32_t p1 = (uint32_t)f2bf(v0.z) | ((uint32_t)f2bf(v0.w) << 16);
        uint32_t p2 = (uint32_t)f2bf(v1.x) | ((uint32_t)f2bf(v1.y) << 16);
        uint32_t p3 = (uint32_t)f2bf(v1.z) | ((uint32_t)f2bf(v1.w) << 16);
        ((uint32_t*)aw0)[0] = p0;
        ((uint32_t*)aw0)[1] = p1;
        ((uint32_t*)aw1)[0] = p2;
        ((uint32_t*)aw1)[1] = p3;
        __syncthreads();
        // ---- compute: 2 k-halves x (2 x 4) fragments
#pragma unroll
        for (int ks = 0; ks < 2; ++ks) {
            const int koffb = ks * 64 + ((l >> 4) << 4);
            bf16x8 af[2], bv[4];
#pragma unroll
            for (int im = 0; im < 2; ++im) {
                const int r = im * 16 + (l & 15);
                af[im] = *(const bf16x8*)((const char*)Alds +
                                          ((r * 128 + koffb) ^ ((r & 7) << 4)));
            }
#pragma unroll
            for (int jn = 0; jn < 4; ++jn) {
                const int n = w * 64 + jn * 16 + (l & 15);
                bv[jn] = *(const bf16x8*)((const char*)Blds +
                                          ((n * 128 + koffb) ^ ((n & 7) << 4)));
            }
#pragma unroll
            for (int im = 0; im < 2; ++im)
#pragma unroll
                for (int jn = 0; jn < 4; ++jn)
                    acc[im][jn] = __builtin_amdgcn_mfma_f32_16x16x32_bf16(
                        af[im], bv[jn], acc[im][jn], 0, 0, 0);
        }
    }

    // ---- epilogue.  C/D frag: col = l&15, row = (l>>4)*4 + reg  [m89]
    if (MODE == 0) {
        float* Og = (float*)Outp;
#pragma unroll
        for (int im = 0; im < 2; ++im) {
            const int row0 = m0 + im * 16 + ((l >> 4) << 2);
#pragma unroll
            for (int jn = 0; jn < 4; ++jn) {
                const int col = w * 64 + jn * 16 + (l & 15);
#pragma unroll
                for (int r = 0; r < 4; ++r) {
                    const float v = acc[im][jn][r];
                    Og[(size_t)(row0 + r) * 256 + col] = v > 0.f ? v : 0.f;
                }
            }
        }
    } else {
        unsigned short* dkT = (unsigned short*)Outp;
#pragma unroll
        for (int im = 0; im < 2; ++im) {
            const int mb = m0 + im * 16 + ((l >> 4) << 2);
#pragma unroll
            for (int jn = 0; jn < 4; ++jn) {
                const int n = w * 64 + jn * 16 + (l & 15);
                const uint32_t lo = (uint32_t)f2bf(acc[im][jn][0]) |
                                    ((uint32_t)f2bf(acc[im][jn][1]) << 16);
                const uint32_t hi = (uint32_t)f2bf(acc[im][jn][2]) |
                                    ((uint32_t)f2bf(acc[im][jn][3]) << 16);
                uint32_t* dst = (uint32_t*)&dkT[(size_t)n * 8192 + mb];
                dst[0] = lo;
                dst[1] = hi;
            }
        }
    }
}

// ---------------------------------------------------------------------------
extern "C" void kernel_launch(void* const* d_in, const int* in_sizes, int n_in,
                              void* d_out, int out_size, void* d_ws, size_t ws_size,
                              hipStream_t stream) {
    const float* data = (const float*)d_in[0];  // [1,8192,256] fp32
    const float* adj = (const float*)d_in[1];   // [1,8192,8192] fp32
    const float* Wk = (const float*)d_in[2];    // [256,256] fp32
    float* out = (float*)d_out;                 // [1,8192,256] fp32

    unsigned short* WT = (unsigned short*)d_ws;                       // 128 KB bf16 W^T
    unsigned short* dkT = (unsigned short*)((char*)d_ws + 131072);    // 4 MB bf16 (data@W)^T

    // 1) W^T in bf16
    wt_kernel<<<64, 256, 0, stream>>>(Wk, WT);
    // 2) dkT[n][m] = (data @ W)^T   : M=8192, N=256, K=256
    gemm_kernel<256, 256, 4, 1><<<256, 256, 0, stream>>>(data, WT, dkT);
    // 3) out = relu(adj @ dk)       : M=8192, N=256, K=8192
    gemm_kernel<8192, 8192, 128, 0><<<256, 256, 0, stream>>>(adj, dkT, out);
}

// Round 3
// 124.471 us; speedup vs baseline: 1.4044x; 1.4044x over previous
//
#include <hip/hip_runtime.h>
#include <stdint.h>

#define AS1 __attribute__((address_space(1)))
#define AS3 __attribute__((address_space(3)))

typedef float f32x4 __attribute__((ext_vector_type(4)));
typedef __bf16 bf16x8 __attribute__((ext_vector_type(8)));

// fp32 -> bf16, round-to-nearest-even (inputs are finite; no NaN handling needed)
__device__ __forceinline__ unsigned short f2bf(float f) {
    uint32_t x = __float_as_uint(f);
    x += 0x7FFFu + ((x >> 16) & 1u);
    return (unsigned short)(x >> 16);
}

__device__ __forceinline__ void gload_lds16(const void* g, void* l) {
    __builtin_amdgcn_global_load_lds((const AS1 void*)g, (AS3 void*)l, 16, 0, 0);
}

// ---------------------------------------------------------------------------
// Kernel 0: WT[n][f] = bf16(W[f][n]).  W is [256][256] fp32 row-major.
// ---------------------------------------------------------------------------
__global__ __launch_bounds__(256) void wt_kernel(const float* __restrict__ W,
                                                 unsigned short* __restrict__ WT) {
    __shared__ float tile[32][33];
    const int bf = blockIdx.x & 7;   // f-tile
    const int bn = blockIdx.x >> 3;  // n-tile
    const int t = threadIdx.x;
    const int c = t & 31, r = t >> 5;  // r in 0..7
#pragma unroll
    for (int i = 0; i < 4; ++i)
        tile[r + i * 8][c] = W[(bf * 32 + r + i * 8) * 256 + bn * 32 + c];
    __syncthreads();
#pragma unroll
    for (int i = 0; i < 4; ++i)
        WT[(bn * 32 + r + i * 8) * 256 + bf * 32 + c] = f2bf(tile[c][r + i * 8]);
}

// ---------------------------------------------------------------------------
// GEMM: D[m][n] = sum_k A[m][k] * B[n][k]   (B given row-major over n, i.e. B^T)
//   A: fp32, converted to bf16 in-flight (reg-stage + swizzled ds_write)
//   B: bf16, staged via global_load_lds with pre-swizzled per-lane source
// Tile: BM=32, BN=256 (full N), BK=64. 256 threads = 4 waves, wave tile 32x64.
// KSPLIT blocks cooperate on one M-tile (disjoint K ranges of KSTEPS*64 each).
// MODE 0: fp32 store of partial (relu only if KSPLIT==1). ks==0 -> Out0,
//         ks>0 -> Pws + (ks-1)*2M floats.
// MODE 1: bf16 transposed store Out0[n][m] (ld 8192), KSPLIT must be 1.
// ---------------------------------------------------------------------------
template <int LDA, int LDB, int KSTEPS, int MODE, int KSPLIT>
__global__ __launch_bounds__(256) void gemm_kernel(const float* __restrict__ A,
                                                   const unsigned short* __restrict__ B,
                                                   float* __restrict__ Out0,
                                                   float* __restrict__ Pws) {
    __shared__ unsigned short Alds[32 * 64];   // 4 KB  (swizzled rows, stride 128 B)
    __shared__ unsigned short Blds[256 * 64];  // 32 KB (swizzled rows, stride 128 B)

    const int t = threadIdx.x;
    const int w = t >> 6;
    const int l = t & 63;
    const int mtile = blockIdx.x / KSPLIT;
    const int ks = blockIdx.x % KSPLIT;
    const int m0 = mtile * 32;
    const int kbase = ks * KSTEPS * 64;

    // A staging mapping: thread t loads row ar, k in [kq*4, kq*4+4) and [32+kq*4, ...)
    const int ar = t >> 3;  // 0..31
    const int kq = t & 7;   // 0..7
    const float* gA = A + (size_t)(m0 + ar) * LDA + kbase + kq * 4;
    char* aw0 = (char*)Alds + ((ar * 128 + kq * 8) ^ ((ar & 7) << 4));
    char* aw1 = (char*)Alds + ((ar * 128 + 64 + kq * 8) ^ ((ar & 7) << 4));

    // B staging mapping: per issue i, lane covers chunk c = w*512 + i*64 + l
    const int nr_base = w * 64 + (l >> 3);  // + i*8 per issue
    const int c16 = l & 7;

    f32x4 acc[2][4];
#pragma unroll
    for (int i = 0; i < 2; ++i)
#pragma unroll
        for (int j = 0; j < 4; ++j) acc[i][j] = (f32x4){0.f, 0.f, 0.f, 0.f};

    for (int step = 0; step < KSTEPS; ++step) {
        const int k0 = step * 64;
        __syncthreads();
        // ---- B tile: [256 n][64 k] bf16 via global_load_lds (linear dest,
        //      swizzle achieved by XORing the SOURCE k-chunk with row&7)
#pragma unroll
        for (int i = 0; i < 8; ++i) {
            const int nr = nr_base + i * 8;
            const unsigned short* src =
                B + (size_t)nr * LDB + kbase + k0 + ((c16 ^ (nr & 7)) << 3);
            gload_lds16(src, (char*)Blds + (w * 512 + i * 64) * 16);
        }
        // ---- A tile: [32 m][64 k] fp32 -> bf16, swizzled ds_write
        const f32x4 v0 = *(const f32x4*)(gA + k0);
        const f32x4 v1 = *(const f32x4*)(gA + k0 + 32);
        uint32_t p0 = (uint32_t)f2bf(v0.x) | ((uint32_t)f2bf(v0.y) << 16);
        uint32_t p1 = (uint32_t)f2bf(v0.z) | ((uint32_t)f2bf(v0.w) << 16);
        uint32_t p2 = (uint32_t)f2bf(v1.x) | ((uint32_t)f2bf(v1.y) << 16);
        uint32_t p3 = (uint32_t)f2bf(v1.z) | ((uint32_t)f2bf(v1.w) << 16);
        ((uint32_t*)aw0)[0] = p0;
        ((uint32_t*)aw0)[1] = p1;
        ((uint32_t*)aw1)[0] = p2;
        ((uint32_t*)aw1)[1] = p3;
        __syncthreads();
        // ---- compute: 2 k-halves x (2 x 4) fragments
#pragma unroll
        for (int kh = 0; kh < 2; ++kh) {
            const int koffb = kh * 64 + ((l >> 4) << 4);
            bf16x8 af[2], bv[4];
#pragma unroll
            for (int im = 0; im < 2; ++im) {
                const int r = im * 16 + (l & 15);
                af[im] = *(const bf16x8*)((const char*)Alds +
                                          ((r * 128 + koffb) ^ ((r & 7) << 4)));
            }
#pragma unroll
            for (int jn = 0; jn < 4; ++jn) {
                const int n = w * 64 + jn * 16 + (l & 15);
                bv[jn] = *(const bf16x8*)((const char*)Blds +
                                          ((n * 128 + koffb) ^ ((n & 7) << 4)));
            }
#pragma unroll
            for (int im = 0; im < 2; ++im)
#pragma unroll
                for (int jn = 0; jn < 4; ++jn)
                    acc[im][jn] = __builtin_amdgcn_mfma_f32_16x16x32_bf16(
                        af[im], bv[jn], acc[im][jn], 0, 0, 0);
        }
    }

    // ---- epilogue.  C/D frag: col = l&15, row = (l>>4)*4 + reg  [m89]
    if (MODE == 0) {
        float* Og = (KSPLIT == 1 || ks == 0)
                        ? Out0
                        : (Pws + (size_t)(ks - 1) * (8192 * 256));
#pragma unroll
        for (int im = 0; im < 2; ++im) {
            const int row0 = m0 + im * 16 + ((l >> 4) << 2);
#pragma unroll
            for (int jn = 0; jn < 4; ++jn) {
                const int col = w * 64 + jn * 16 + (l & 15);
#pragma unroll
                for (int r = 0; r < 4; ++r) {
                    float v = acc[im][jn][r];
                    if (KSPLIT == 1) v = v > 0.f ? v : 0.f;
                    Og[(size_t)(row0 + r) * 256 + col] = v;
                }
            }
        }
    } else {
        unsigned short* dkT = (unsigned short*)Out0;
#pragma unroll
        for (int im = 0; im < 2; ++im) {
            const int mb = m0 + im * 16 + ((l >> 4) << 2);
#pragma unroll
            for (int jn = 0; jn < 4; ++jn) {
                const int n = w * 64 + jn * 16 + (l & 15);
                const uint32_t lo = (uint32_t)f2bf(acc[im][jn][0]) |
                                    ((uint32_t)f2bf(acc[im][jn][1]) << 16);
                const uint32_t hi = (uint32_t)f2bf(acc[im][jn][2]) |
                                    ((uint32_t)f2bf(acc[im][jn][3]) << 16);
                uint32_t* dst = (uint32_t*)&dkT[(size_t)n * 8192 + mb];
                dst[0] = lo;
                dst[1] = hi;
            }
        }
    }
}

// ---------------------------------------------------------------------------
// out = relu(out + sum_{s} P[s])   over 8192*256 fp32, vectorized f32x4.
// ---------------------------------------------------------------------------
template <int S>
__global__ __launch_bounds__(256) void reduce_relu_kernel(float* __restrict__ out,
                                                          const float* __restrict__ P) {
    const int i = blockIdx.x * 256 + threadIdx.x;  // f32x4 index, 524288 total
    f32x4 v = ((const f32x4*)out)[i];
#pragma unroll
    for (int s = 0; s < S - 1; ++s) {
        const f32x4 p = ((const f32x4*)P)[(size_t)s * 524288 + i];
        v.x += p.x; v.y += p.y; v.z += p.z; v.w += p.w;
    }
    v.x = v.x > 0.f ? v.x : 0.f;
    v.y = v.y > 0.f ? v.y : 0.f;
    v.z = v.z > 0.f ? v.z : 0.f;
    v.w = v.w > 0.f ? v.w : 0.f;
    ((f32x4*)out)[i] = v;
}

// ---------------------------------------------------------------------------
extern "C" void kernel_launch(void* const* d_in, const int* in_sizes, int n_in,
                              void* d_out, int out_size, void* d_ws, size_t ws_size,
                              hipStream_t stream) {
    const float* data = (const float*)d_in[0];  // [1,8192,256] fp32
    const float* adj = (const float*)d_in[1];   // [1,8192,8192] fp32
    const float* Wk = (const float*)d_in[2];    // [256,256] fp32
    float* out = (float*)d_out;                 // [1,8192,256] fp32

    unsigned short* WT = (unsigned short*)d_ws;                     // 128 KB bf16 W^T
    unsigned short* dkT = (unsigned short*)((char*)d_ws + 131072);  // 4 MB bf16 (data@W)^T
    float* P = (float*)((char*)d_ws + 131072 + 4194304);            // split-K partials

    const size_t base_need = 131072 + 4194304;
    const size_t part_bytes = (size_t)8192 * 256 * 4;  // 8 MB per extra split

    // 1) W^T in bf16
    wt_kernel<<<64, 256, 0, stream>>>(Wk, WT);
    // 2) dkT[n][m] = (data @ W)^T   : M=8192, N=256, K=256
    gemm_kernel<256, 256, 4, 1, 1><<<256, 256, 0, stream>>>(data, WT, (float*)dkT, nullptr);
    // 3) out = relu(adj @ dk)       : M=8192, N=256, K=8192
    //    split-K=4 -> grid 1024 -> 4 blocks/CU resident (TLP hides HBM latency)
    if (ws_size >= base_need + 3 * part_bytes) {
        gemm_kernel<8192, 8192, 32, 0, 4><<<1024, 256, 0, stream>>>(adj, dkT, out, P);
        reduce_relu_kernel<4><<<2048, 256, 0, stream>>>(out, P);
    } else if (ws_size >= base_need + part_bytes) {
        gemm_kernel<8192, 8192, 64, 0, 2><<<512, 256, 0, stream>>>(adj, dkT, out, P);
        reduce_relu_kernel<2><<<2048, 256, 0, stream>>>(out, P);
    } else {
        gemm_kernel<8192, 8192, 128, 0, 1><<<256, 256, 0, stream>>>(adj, dkT, out, nullptr);
    }
}

// Round 4
// 122.126 us; speedup vs baseline: 1.4313x; 1.0192x over previous
//
#include <hip/hip_runtime.h>
#include <stdint.h>

#define AS1 __attribute__((address_space(1)))
#define AS3 __attribute__((address_space(3)))

typedef float f32x4 __attribute__((ext_vector_type(4)));
typedef __bf16 bf16x8 __attribute__((ext_vector_type(8)));

// fp32 -> bf16, round-to-nearest-even (inputs are finite; no NaN handling needed)
__device__ __forceinline__ unsigned short f2bf(float f) {
    uint32_t x = __float_as_uint(f);
    x += 0x7FFFu + ((x >> 16) & 1u);
    return (unsigned short)(x >> 16);
}

__device__ __forceinline__ void gload_lds16(const void* g, void* l) {
    __builtin_amdgcn_global_load_lds((const AS1 void*)g, (AS3 void*)l, 16, 0, 0);
}

// ---------------------------------------------------------------------------
// Kernel 0: WT[n][f] = bf16(W[f][n]).  W is [256][256] fp32 row-major.
// ---------------------------------------------------------------------------
__global__ __launch_bounds__(256) void wt_kernel(const float* __restrict__ W,
                                                 unsigned short* __restrict__ WT) {
    __shared__ float tile[32][33];
    const int bf = blockIdx.x & 7;   // f-tile
    const int bn = blockIdx.x >> 3;  // n-tile
    const int t = threadIdx.x;
    const int c = t & 31, r = t >> 5;  // r in 0..7
#pragma unroll
    for (int i = 0; i < 4; ++i)
        tile[r + i * 8][c] = W[(bf * 32 + r + i * 8) * 256 + bn * 32 + c];
    __syncthreads();
#pragma unroll
    for (int i = 0; i < 4; ++i)
        WT[(bn * 32 + r + i * 8) * 256 + bf * 32 + c] = f2bf(tile[c][r + i * 8]);
}

// ---------------------------------------------------------------------------
// GEMM: D[m][n] = sum_k A[m][k] * B[n][k]   (B given row-major over n, i.e. B^T)
//   A: fp32, staged RAW via global_load_lds (swizzled per-lane source, linear
//      LDS dest); converted fp32->bf16 at fragment-read time (compiler cvt_pk).
//   B: bf16, staged via global_load_lds with pre-swizzled per-lane source.
// Tile: BM=32, BN=256 (full N), BK=64. 256 threads = 4 waves, wave tile 32x64.
// KSPLIT blocks cooperate on one M-tile (disjoint K ranges of KSTEPS*64 each).
// MODE 0: fp32 store of partial (relu only if KSPLIT==1). ks==0 -> Out0,
//         ks>0 -> Pws + (ks-1)*2M floats.
// MODE 1: bf16 transposed store Out0[n][m] (ld 8192), KSPLIT must be 1.
// ---------------------------------------------------------------------------
template <int LDA, int LDB, int KSTEPS, int MODE, int KSPLIT>
__global__ __launch_bounds__(256) void gemm_kernel(const float* __restrict__ A,
                                                   const unsigned short* __restrict__ B,
                                                   float* __restrict__ Out0,
                                                   float* __restrict__ Pws) {
    __shared__ float Afp[32 * 64];             // 8 KB fp32 (swizzled 16B chunks/row)
    __shared__ unsigned short Blds[256 * 64];  // 32 KB (swizzled rows, stride 128 B)

    const int t = threadIdx.x;
    const int w = t >> 6;
    const int l = t & 63;
    const int mtile = blockIdx.x / KSPLIT;
    const int ks = blockIdx.x % KSPLIT;
    const int m0 = mtile * 32;
    const int kbase = ks * KSTEPS * 64;

    // ---- A staging map (issue j=0,1): chunk = j*256 + w*64 + l (16B chunks,
    //      16/row). row = j*16 + w*4 + (l>>4), col-chunk c = l&15; source chunk
    //      is XOR-swizzled so the linear LDS dest ends up swizzled.
    const int rowj0 = w * 4 + (l >> 4);  // row for issue 0; +16 for issue 1
    const int ca = l & 15;
    const float* gAs = A + (size_t)(m0 + rowj0) * LDA + kbase +
                       ((ca ^ (rowj0 & 7)) << 2);
    char* ldsA0 = (char*)Afp + w * 1024;
    char* ldsA1 = ldsA0 + 4096;

    // ---- B staging map: per issue i, lane covers chunk c = w*512 + i*64 + l
    const int nr_base = w * 64 + (l >> 3);  // + i*8 per issue
    const int c16 = l & 7;

    f32x4 acc[2][4];
#pragma unroll
    for (int i = 0; i < 2; ++i)
#pragma unroll
        for (int j = 0; j < 4; ++j) acc[i][j] = (f32x4){0.f, 0.f, 0.f, 0.f};

    for (int step = 0; step < KSTEPS; ++step) {
        const int k0 = step * 64;
        __syncthreads();
        // ---- B tile: [256 n][64 k] bf16 via global_load_lds
#pragma unroll
        for (int i = 0; i < 8; ++i) {
            const int nr = nr_base + i * 8;
            const unsigned short* src =
                B + (size_t)nr * LDB + kbase + k0 + ((c16 ^ (nr & 7)) << 3);
            gload_lds16(src, (char*)Blds + (w * 512 + i * 64) * 16);
        }
        // ---- A tile: [32 m][64 k] fp32 via global_load_lds (raw, no cvt)
        gload_lds16(gAs + k0, ldsA0);
        gload_lds16(gAs + (size_t)16 * LDA + k0, ldsA1);
        __syncthreads();  // compiler drains vmcnt(0) before barrier
        // ---- compute: 2 k-halves x (2 x 4) fragments
#pragma unroll
        for (int kh = 0; kh < 2; ++kh) {
            bf16x8 af[2], bv[4];
#pragma unroll
            for (int im = 0; im < 2; ++im) {
                const int r = im * 16 + (l & 15);
                const int cb = kh * 8 + ((l >> 4) << 1);
                const char* base = (const char*)Afp + r * 256;
                const int sw = (r & 7) << 4;
                const f32x4 u0 = *(const f32x4*)(base + ((cb << 4) ^ sw));
                const f32x4 u1 = *(const f32x4*)(base + (((cb + 1) << 4) ^ sw));
                bf16x8 a;
                a[0] = (__bf16)u0.x; a[1] = (__bf16)u0.y;
                a[2] = (__bf16)u0.z; a[3] = (__bf16)u0.w;
                a[4] = (__bf16)u1.x; a[5] = (__bf16)u1.y;
                a[6] = (__bf16)u1.z; a[7] = (__bf16)u1.w;
                af[im] = a;
            }
            const int koffb = kh * 64 + ((l >> 4) << 4);
#pragma unroll
            for (int jn = 0; jn < 4; ++jn) {
                const int n = w * 64 + jn * 16 + (l & 15);
                bv[jn] = *(const bf16x8*)((const char*)Blds +
                                          ((n * 128 + koffb) ^ ((n & 7) << 4)));
            }
#pragma unroll
            for (int im = 0; im < 2; ++im)
#pragma unroll
                for (int jn = 0; jn < 4; ++jn)
                    acc[im][jn] = __builtin_amdgcn_mfma_f32_16x16x32_bf16(
                        af[im], bv[jn], acc[im][jn], 0, 0, 0);
        }
    }

    // ---- epilogue.  C/D frag: col = l&15, row = (l>>4)*4 + reg  [m89]
    if (MODE == 0) {
        float* Og = (KSPLIT == 1 || ks == 0)
                        ? Out0
                        : (Pws + (size_t)(ks - 1) * (8192 * 256));
#pragma unroll
        for (int im = 0; im < 2; ++im) {
            const int row0 = m0 + im * 16 + ((l >> 4) << 2);
#pragma unroll
            for (int jn = 0; jn < 4; ++jn) {
                const int col = w * 64 + jn * 16 + (l & 15);
#pragma unroll
                for (int r = 0; r < 4; ++r) {
                    float v = acc[im][jn][r];
                    if (KSPLIT == 1) v = v > 0.f ? v : 0.f;
                    Og[(size_t)(row0 + r) * 256 + col] = v;
                }
            }
        }
    } else {
        unsigned short* dkT = (unsigned short*)Out0;
#pragma unroll
        for (int im = 0; im < 2; ++im) {
            const int mb = m0 + im * 16 + ((l >> 4) << 2);
#pragma unroll
            for (int jn = 0; jn < 4; ++jn) {
                const int n = w * 64 + jn * 16 + (l & 15);
                const uint32_t lo = (uint32_t)f2bf(acc[im][jn][0]) |
                                    ((uint32_t)f2bf(acc[im][jn][1]) << 16);
                const uint32_t hi = (uint32_t)f2bf(acc[im][jn][2]) |
                                    ((uint32_t)f2bf(acc[im][jn][3]) << 16);
                uint32_t* dst = (uint32_t*)&dkT[(size_t)n * 8192 + mb];
                dst[0] = lo;
                dst[1] = hi;
            }
        }
    }
}

// ---------------------------------------------------------------------------
// out = relu(out + sum_{s} P[s])   over 8192*256 fp32, vectorized f32x4.
// ---------------------------------------------------------------------------
template <int S>
__global__ __launch_bounds__(256) void reduce_relu_kernel(float* __restrict__ out,
                                                          const float* __restrict__ P) {
    const int i = blockIdx.x * 256 + threadIdx.x;  // f32x4 index, 524288 total
    f32x4 v = ((const f32x4*)out)[i];
#pragma unroll
    for (int s = 0; s < S - 1; ++s) {
        const f32x4 p = ((const f32x4*)P)[(size_t)s * 524288 + i];
        v.x += p.x; v.y += p.y; v.z += p.z; v.w += p.w;
    }
    v.x = v.x > 0.f ? v.x : 0.f;
    v.y = v.y > 0.f ? v.y : 0.f;
    v.z = v.z > 0.f ? v.z : 0.f;
    v.w = v.w > 0.f ? v.w : 0.f;
    ((f32x4*)out)[i] = v;
}

// ---------------------------------------------------------------------------
extern "C" void kernel_launch(void* const* d_in, const int* in_sizes, int n_in,
                              void* d_out, int out_size, void* d_ws, size_t ws_size,
                              hipStream_t stream) {
    const float* data = (const float*)d_in[0];  // [1,8192,256] fp32
    const float* adj = (const float*)d_in[1];   // [1,8192,8192] fp32
    const float* Wk = (const float*)d_in[2];    // [256,256] fp32
    float* out = (float*)d_out;                 // [1,8192,256] fp32

    unsigned short* WT = (unsigned short*)d_ws;                     // 128 KB bf16 W^T
    unsigned short* dkT = (unsigned short*)((char*)d_ws + 131072);  // 4 MB bf16 (data@W)^T
    float* P = (float*)((char*)d_ws + 131072 + 4194304);            // split-K partials

    const size_t base_need = 131072 + 4194304;
    const size_t part_bytes = (size_t)8192 * 256 * 4;  // 8 MB per extra split

    // 1) W^T in bf16
    wt_kernel<<<64, 256, 0, stream>>>(Wk, WT);
    // 2) dkT[n][m] = (data @ W)^T   : M=8192, N=256, K=256
    gemm_kernel<256, 256, 4, 1, 1><<<256, 256, 0, stream>>>(data, WT, (float*)dkT, nullptr);
    // 3) out = relu(adj @ dk)       : M=8192, N=256, K=8192
    //    split-K=4 -> grid 1024 -> up to 4 blocks/CU resident (TLP hides latency)
    if (ws_size >= base_need + 3 * part_bytes) {
        gemm_kernel<8192, 8192, 32, 0, 4><<<1024, 256, 0, stream>>>(adj, dkT, out, P);
        reduce_relu_kernel<4><<<2048, 256, 0, stream>>>(out, P);
    } else if (ws_size >= base_need + part_bytes) {
        gemm_kernel<8192, 8192, 64, 0, 2><<<512, 256, 0, stream>>>(adj, dkT, out, P);
        reduce_relu_kernel<2><<<2048, 256, 0, stream>>>(out, P);
    } else {
        gemm_kernel<8192, 8192, 128, 0, 1><<<256, 256, 0, stream>>>(adj, dkT, out, nullptr);
    }
}